// Round 8
// baseline (403.067 us; speedup 1.0000x reference)
//
#include <hip/hip_runtime.h>
#include <math.h>

// Problem shape (TransformerDecoderLayer_9569187135641) — fp32 I/O,
// bf16 MFMA internals.
#define Bn   64
#define Tn   100
#define Tp   128          // T padded to MFMA tiling
#define Dn   1024
#define Hn   16
#define HDn  64
#define DFFn 4096
#define EPSf 1e-5f

typedef unsigned short ushort_t;
typedef __attribute__((ext_vector_type(8))) __bf16 bf16x8;
typedef __attribute__((ext_vector_type(4))) float f32x4;

__device__ __forceinline__ float u2f(ushort_t u) {
    union { unsigned int i; float f; } v; v.i = ((unsigned int)u) << 16; return v.f;
}
__device__ __forceinline__ ushort_t f2bf(float f) {   // RNE f32 -> bf16 bits
    union { float f; unsigned int u; } v; v.f = f;
    unsigned int r = v.u + 0x7FFFu + ((v.u >> 16) & 1u);
    return (ushort_t)(r >> 16);
}

// async global(16B/lane) -> LDS; LDS dest = wave-uniform base + lane*16.
__device__ __forceinline__ void gload_lds16(const void* g, void* l) {
    __builtin_amdgcn_global_load_lds(
        (const __attribute__((address_space(1))) unsigned int*)g,
        (__attribute__((address_space(3))) unsigned int*)l,
        16, 0, 0);
}

#define VMWAIT_(n) asm volatile("s_waitcnt vmcnt(" #n ")" ::: "memory")
#define VMWAIT(n)  VMWAIT_(n)

// ---------------------------------------------------------------------------
// Fused fp32 -> bf16 conversion of up to 5 buffers + RoPE sincos table
// (last block) in one launch. tab[t][f] = (cos, sin)(t * 10000^(-f/16)),
// t < 100, f < 16.
// ---------------------------------------------------------------------------
struct ConvSeg { const float* src; ushort_t* dst; int n4; };
struct Conv5   { ConvSeg seg[5]; float2* tab; };

__global__ __launch_bounds__(256) void conv_bf16_multi(Conv5 cfg)
{
    if (blockIdx.x == gridDim.x - 1) {
        for (int e = threadIdx.x; e < Tn * 16; e += 256) {
            const int t = e >> 4, f = e & 15;
            float s, c;
            sincosf((float)t * exp2f(-0.83048202f * (float)f), &s, &c);
            cfg.tab[e] = make_float2(c, s);
        }
        return;
    }
    int i = blockIdx.x * 256 + threadIdx.x;
    #pragma unroll
    for (int s = 0; s < 5; ++s) {
        const int n = cfg.seg[s].n4;
        if (i < n) {
            float4 v = ((const float4*)cfg.seg[s].src)[i];
            ushort4 o;
            o.x = f2bf(v.x); o.y = f2bf(v.y); o.z = f2bf(v.z); o.w = f2bf(v.w);
            ((ushort4*)cfg.seg[s].dst)[i] = o;
            return;
        }
        i -= n;
    }
}

// ---------------------------------------------------------------------------
// Tile map (shared): swz=1 -> XCD-affinity (groups of 8 row-tiles; all
// col-blocks of one row land on one XCD). swz=0 -> plain col-fast linear.
// ---------------------------------------------------------------------------
#define GEMM_TILE_MAP(gx_, gy_, swz_)                                        \
    const int L  = blockIdx.x;                                               \
    int rowt, colt;                                                          \
    if (swz_) {                                                              \
        const int group = L / (8 * (gx_));                                   \
        int l = L - group * 8 * (gx_);                                       \
        const int rem = (gy_) - group * 8;                                   \
        if (rem >= 8) { rowt = group * 8 + (l & 7); colt = l >> 3; }         \
        else          { rowt = group * 8 + l % rem; colt = l / rem; }        \
    } else { rowt = L / (gx_); colt = L - rowt * (gx_); }

// ---------------------------------------------------------------------------
// 128x128 2-phase pipelined core (r7-verified on Wo K=1024 and W2 K=4096):
// 4 waves (2x2, per-wave 64x64), BK=64, LDS 64 KiB -> 2 blocks/CU
// co-resident. Counted-vmcnt schedule; cross-block overlap hides the
// per-phase stall that limits 1-block/CU cores to ~43% SIMD-MFMA-busy.
// Per K-tile: P0 (m0..1, 16 MFMA/wave): read bfr+af0, stage A(t+1);
//             P1 (m2..3, 16 MFMA/wave): read af1, stage B(t+2); vmcnt(4).
// XOR-chunk source-side swizzle (SQ_LDS_BANK_CONFLICT = 0).
// ---------------------------------------------------------------------------
template<bool RELU, bool ADDRES, typename OutT>
__global__ __launch_bounds__(256, 2) void gemm128_2p(const ushort_t* __restrict__ A,
                                                     const ushort_t* __restrict__ Bm,
                                                     const float* __restrict__ bias,
                                                     const ushort_t* __restrict__ res,
                                                     OutT* __restrict__ C,
                                                     int M, int N, int K,
                                                     int gx, int swz)
{
    __shared__ __align__(16) ushort_t As[2][128 * 64];
    __shared__ __align__(16) ushort_t Bs[2][128 * 64];

    const int gy = M >> 7;
    GEMM_TILE_MAP(gx, gy, swz)

    const int tid  = threadIdx.x;
    const int lane = tid & 63;
    const int wave = tid >> 6;
    const int wrow = (wave >> 1) * 64;
    const int wcol = (wave & 1) * 64;
    const int row0 = rowt * 128;
    const int col0 = colt * 128;
    const int frow = lane & 15;
    const int g    = lane >> 4;

    auto stage = [&](const ushort_t* src, int rowbase, ushort_t* lds) {
        #pragma unroll
        for (int i = 0; i < 4; ++i) {
            const int idx = i * 256 + tid;
            const int row = idx >> 3;
            const int gc  = (idx & 7) ^ (row & 7);
            gload_lds16(src + (size_t)(rowbase + row) * K + gc * 8, lds + idx * 8);
        }
    };

    f32x4 acc[4][4] = {};

    const int NT = K >> 6;
    // prologue: B(0), A(0), B(1); wait until B(0)+A(0) landed (B(1) flies).
    stage(Bm,      col0, &Bs[0][0]);
    stage(A,       row0, &As[0][0]);
    stage(Bm + 64, col0, &Bs[1][0]);
    VMWAIT(4);
    __builtin_amdgcn_s_barrier();

    for (int t = 0; t < NT; ++t) {
        const int  buf = t & 1;
        const bool stA = (t + 1 < NT);
        const bool stB = (t + 2 < NT);

        bf16x8 bfr[4][2];
        #pragma unroll
        for (int j = 0; j < 4; ++j)
            #pragma unroll
            for (int kk = 0; kk < 2; ++kk) {
                const int rb = wcol + j * 16 + frow;
                const int ch = kk * 4 + g;
                bfr[j][kk] = *(const bf16x8*)&Bs[buf][rb * 64 + (ch ^ (rb & 7)) * 8];
            }
        // ---- P0: m-frags 0..1 ----
        bf16x8 af0[2][2];
        #pragma unroll
        for (int m = 0; m < 2; ++m)
            #pragma unroll
            for (int kk = 0; kk < 2; ++kk) {
                const int ra = wrow + m * 16 + frow;
                const int ch = kk * 4 + g;
                af0[m][kk] = *(const bf16x8*)&As[buf][ra * 64 + (ch ^ (ra & 7)) * 8];
            }
        if (stA) stage(A + (t + 1) * 64, row0, &As[buf ^ 1][0]);
        __builtin_amdgcn_s_barrier();
        asm volatile("s_waitcnt lgkmcnt(0)" ::: "memory");
        __builtin_amdgcn_sched_barrier(0);
        __builtin_amdgcn_s_setprio(1);
        #pragma unroll
        for (int m = 0; m < 2; ++m)
            #pragma unroll
            for (int j = 0; j < 4; ++j)
                #pragma unroll
                for (int kk = 0; kk < 2; ++kk)
                    acc[m][j] = __builtin_amdgcn_mfma_f32_16x16x32_bf16(
                        af0[m][kk], bfr[j][kk], acc[m][j], 0, 0, 0);
        __builtin_amdgcn_s_setprio(0);
        __builtin_amdgcn_sched_barrier(0);
        __builtin_amdgcn_s_barrier();

        // ---- P1: m-frags 2..3 ----
        bf16x8 af1[2][2];
        #pragma unroll
        for (int m = 0; m < 2; ++m)
            #pragma unroll
            for (int kk = 0; kk < 2; ++kk) {
                const int ra = wrow + (2 + m) * 16 + frow;
                const int ch = kk * 4 + g;
                af1[m][kk] = *(const bf16x8*)&As[buf][ra * 64 + (ch ^ (ra & 7)) * 8];
            }
        if (stB) stage(Bm + (t + 2) * 64, col0, &Bs[buf][0]);
        __builtin_amdgcn_s_barrier();
        asm volatile("s_waitcnt lgkmcnt(0)" ::: "memory");
        __builtin_amdgcn_sched_barrier(0);
        __builtin_amdgcn_s_setprio(1);
        #pragma unroll
        for (int m = 0; m < 2; ++m)
            #pragma unroll
            for (int j = 0; j < 4; ++j)
                #pragma unroll
                for (int kk = 0; kk < 2; ++kk)
                    acc[2 + m][j] = __builtin_amdgcn_mfma_f32_16x16x32_bf16(
                        af1[m][kk], bfr[j][kk], acc[2 + m][j], 0, 0, 0);
        __builtin_amdgcn_s_setprio(0);
        __builtin_amdgcn_sched_barrier(0);
        if (stB)      { VMWAIT(4); }
        else if (stA) { VMWAIT(0); }
        __builtin_amdgcn_s_barrier();
    }

    const int crow = (lane >> 4) * 4;
    const int ccol = lane & 15;
    #pragma unroll
    for (int i = 0; i < 4; ++i) {
        #pragma unroll
        for (int r = 0; r < 4; ++r) {
            const int row = row0 + wrow + i * 16 + crow + r;
            #pragma unroll
            for (int j = 0; j < 4; ++j) {
                const int col = col0 + wcol + j * 16 + ccol;
                float v = acc[i][j][r] + bias[col];
                if constexpr (ADDRES) v += u2f(res[(size_t)row * N + col]);
                if constexpr (RELU) v = fmaxf(v, 0.f);
                if constexpr (sizeof(OutT) == 2)
                    C[(size_t)row * N + col] = (OutT)f2bf(v);
                else
                    C[(size_t)row * N + col] = (OutT)v;
            }
        }
    }
}

// ---------------------------------------------------------------------------
// RoPE + head-split + V-transpose, decoupled from the GEMM (r5 post-mortem:
// the fused epilogue was the qkv bottleneck, invariant to K-loop structure).
// One block per (b,h). Reads qkvb[6400][3072]; writes:
//   q,k: (bh, t<100, 64)   — RoPE'd, coalesced 2B stores in 64B runs
//   vt:  (bh, d, t padded to 128) — transposed via padded LDS (conflict-free),
//        256B contiguous row stores, pad t in [100,128) zero-filled.
// ---------------------------------------------------------------------------
__global__ __launch_bounds__(256) void rope_split(const ushort_t* __restrict__ qkv,
                                                  const float2*  __restrict__ tab,
                                                  ushort_t* __restrict__ q,
                                                  ushort_t* __restrict__ k,
                                                  ushort_t* __restrict__ vt)
{
    __shared__ ushort_t vls[64 * 130];           // padded: stride 130 ushorts

    const int bh  = blockIdx.x;                  // 0..1023
    const int b   = bh >> 4, h = bh & 15;
    const int tid = threadIdx.x;
    const size_t rowbase = (size_t)b * Tn * (3 * Dn) + h * HDn;

    // ---- v load (coalesced) -> LDS transposed ----
    const ushort_t* vsrc = qkv + rowbase + 2 * Dn;
    for (int idx = tid; idx < Tn * 64; idx += 256) {
        const int t = idx >> 6, d = idx & 63;
        vls[d * 130 + t] = vsrc[(size_t)t * (3 * Dn) + d];
    }

    // ---- q and k with RoPE (no LDS dependency) ----
    #pragma unroll
    for (int s = 0; s < 2; ++s) {
        const ushort_t* src = qkv + rowbase + s * Dn;
        ushort_t* dst = (s ? k : q) + (size_t)bh * Tp * HDn;
        for (int idx = tid; idx < Tn * 32; idx += 256) {
            const int t = idx >> 5, p = idx & 31;
            const unsigned int xi =
                *(const unsigned int*)&src[(size_t)t * (3 * Dn) + 2 * p];
            const float x1 = u2f((ushort_t)(xi & 0xffffu));
            const float x2 = u2f((ushort_t)(xi >> 16));
            const float2 cs = tab[t * 16 + (p & 15)];
            dst[t * 64 + p]      = f2bf(x1 * cs.x - x2 * cs.y);
            dst[t * 64 + 32 + p] = f2bf(x1 * cs.y + x2 * cs.x);
        }
    }

    __syncthreads();

    // ---- vt store: 64 rows x 128 cols, contiguous 256B per row ----
    ushort_t* vdst = vt + (size_t)bh * HDn * Tp;
    for (int idx = tid; idx < 64 * 64; idx += 256) {
        const int d  = idx >> 6;
        const int tt = (idx & 63) * 2;
        ushort2 o;
        o.x = (tt     < Tn) ? vls[d * 130 + tt]     : (ushort_t)0;
        o.y = (tt + 1 < Tn) ? vls[d * 130 + tt + 1] : (ushort_t)0;
        *(ushort2*)&vdst[d * Tp + tt] = o;
    }
}

// ---------------------------------------------------------------------------
// MFMA flash attention (r4-verified): one block (4 waves) per (b,h).
// ---------------------------------------------------------------------------
__global__ __launch_bounds__(256) void attn_mfma(const ushort_t* __restrict__ q,
                                                 const ushort_t* __restrict__ k,
                                                 const ushort_t* __restrict__ vt,
                                                 ushort_t* __restrict__ ctx)
{
    __shared__ __align__(16) ushort_t sm[24576];   // 48 KB

    const int bh   = blockIdx.x;
    const int b    = bh >> 4, h = bh & 15;
    const int tid  = threadIdx.x;
    const int wave = tid >> 6;
    const int lane = tid & 63;
    const int c    = lane & 15;
    const int g    = lane >> 4;
    const int R0   = wave * 32;

    const ushort_t* qg = q  + (size_t)bh * Tp * HDn;
    const ushort_t* kg = k  + (size_t)bh * Tp * HDn;
    const ushort_t* vg = vt + (size_t)bh * HDn * Tp;
    for (int s = wave; s < 16; s += 4) {
        const int idx = s * 64 + lane;
        { const int row = idx >> 3, pc = idx & 7, gc = pc ^ (row & 7);
          gload_lds16(qg + row * 64 + gc * 8, &sm[idx * 8]);
          gload_lds16(kg + row * 64 + gc * 8, &sm[8192 + idx * 8]); }
        { const int row = idx >> 4, pc = idx & 15, gc = pc ^ (row & 15);
          gload_lds16(vg + row * 128 + gc * 8, &sm[16384 + idx * 8]); }
    }
    __syncthreads();

    // ---- S = Q K^T ----
    f32x4 acc[2][8] = {};
    #pragma unroll
    for (int ks = 0; ks < 2; ++ks) {
        const int cb = ks * 4;
        bf16x8 aq[2];
        #pragma unroll
        for (int i = 0; i < 2; ++i) {
            const int row = R0 + i * 16 + c;
            const int ph  = (cb + g) ^ (row & 7);
            aq[i] = *(const bf16x8*)&sm[row * 64 + ph * 8];
        }
        #pragma unroll
        for (int j = 0; j < 8; ++j) {
            const int row = j * 16 + c;
            const int ph  = (cb + g) ^ (row & 7);
            const bf16x8 bk = *(const bf16x8*)&sm[8192 + row * 64 + ph * 8];
            acc[0][j] = __builtin_amdgcn_mfma_f32_16x16x32_bf16(aq[0], bk, acc[0][j], 0, 0, 0);
            acc[1][j] = __builtin_amdgcn_mfma_f32_16x16x32_bf16(aq[1], bk, acc[1][j], 0, 0, 0);
        }
    }
    __syncthreads();

    // ---- softmax + P(bf16) into sm[0..16384) ----
    float linv[2][4];
    #pragma unroll
    for (int i = 0; i < 2; ++i) {
        #pragma unroll
        for (int r = 0; r < 4; ++r) {
            const int row = R0 + i * 16 + g * 4 + r;
            float sv[8], m = -1e30f;
            #pragma unroll
            for (int j = 0; j < 8; ++j) {
                const int col = j * 16 + c;
                const float s = acc[i][j][r] * 0.125f;
                sv[j] = (col <= row) ? s : -1e30f;
                m = fmaxf(m, sv[j]);
            }
            #pragma unroll
            for (int msk = 1; msk < 16; msk <<= 1) m = fmaxf(m, __shfl_xor(m, msk));
            float l = 0.f;
            #pragma unroll
            for (int j = 0; j < 8; ++j) {
                const int col = j * 16 + c;
                const float p = (col <= row) ? __expf(sv[j] - m) : 0.f;
                sv[j] = p; l += p;
            }
            #pragma unroll
            for (int msk = 1; msk < 16; msk <<= 1) l += __shfl_xor(l, msk);
            linv[i][r] = 1.f / l;
            #pragma unroll
            for (int j = 0; j < 8; ++j) {
                const int chunk = j * 2 + (c >> 3);
                const int ph    = chunk ^ (row & 15);
                sm[row * 128 + ph * 8 + (c & 7)] = f2bf(sv[j]);
            }
        }
    }
    __syncthreads();

    // ---- ctx = P Vt^T ----
    f32x4 acc2[2][4] = {};
    #pragma unroll
    for (int ks = 0; ks < 4; ++ks) {
        const int cb = ks * 4;
        bf16x8 ap[2];
        #pragma unroll
        for (int i = 0; i < 2; ++i) {
            const int row = R0 + i * 16 + c;
            const int ph  = (cb + g) ^ (row & 15);
            ap[i] = *(const bf16x8*)&sm[row * 128 + ph * 8];
        }
        #pragma unroll
        for (int n = 0; n < 4; ++n) {
            const int row = n * 16 + c;
            const int ph  = (cb + g) ^ (row & 15);
            const bf16x8 bv = *(const bf16x8*)&sm[16384 + row * 128 + ph * 8];
            acc2[0][n] = __builtin_amdgcn_mfma_f32_16x16x32_bf16(ap[0], bv, acc2[0][n], 0, 0, 0);
            acc2[1][n] = __builtin_amdgcn_mfma_f32_16x16x32_bf16(ap[1], bv, acc2[1][n], 0, 0, 0);
        }
    }

    #pragma unroll
    for (int i = 0; i < 2; ++i) {
        #pragma unroll
        for (int r = 0; r < 4; ++r) {
            const int row = R0 + i * 16 + g * 4 + r;
            if (row < Tn) {
                const float s = linv[i][r];
                #pragma unroll
                for (int n = 0; n < 4; ++n) {
                    const int col = n * 16 + c;
                    ctx[(size_t)(b * Tn + row) * Dn + h * HDn + col] =
                        f2bf(acc2[i][n][r] * s);
                }
            }
        }
    }
}

// ---------------------------------------------------------------------------
// LN variants.
// ---------------------------------------------------------------------------
__global__ __launch_bounds__(256) void ln_single(const ushort_t* __restrict__ a,
                                                 const float* __restrict__ g,
                                                 const float* __restrict__ be,
                                                 ushort_t* __restrict__ out_bf)
{
    const int row = blockIdx.x;
    const int tid = threadIdx.x;
    __shared__ float red[256];
    const size_t base = (size_t)row * Dn;

    float vals[4];
    float s = 0.f;
    #pragma unroll
    for (int i = 0; i < 4; ++i) {
        const int c = tid + i * 256;
        vals[i] = u2f(a[base + c]);
        s += vals[i];
    }
    red[tid] = s;
    __syncthreads();
    for (int o = 128; o > 0; o >>= 1) {
        if (tid < o) red[tid] += red[tid + o];
        __syncthreads();
    }
    const float mu = red[0] * (1.f / Dn);
    __syncthreads();

    float vs = 0.f;
    #pragma unroll
    for (int i = 0; i < 4; ++i) { const float d = vals[i] - mu; vs += d * d; }
    red[tid] = vs;
    __syncthreads();
    for (int o = 128; o > 0; o >>= 1) {
        if (tid < o) red[tid] += red[tid + o];
        __syncthreads();
    }
    const float rstd = rsqrtf(red[0] * (1.f / Dn) + EPSf);

    #pragma unroll
    for (int i = 0; i < 4; ++i) {
        const int c = tid + i * 256;
        out_bf[base + c] = f2bf((vals[i] - mu) * rstd * g[c] + be[c]);
    }
}

__global__ __launch_bounds__(256) void add_ln2(const ushort_t* __restrict__ a,
                                               const ushort_t* __restrict__ r,
                                               const float* __restrict__ g,
                                               const float* __restrict__ be,
                                               float* __restrict__ out)
{
    const int row = blockIdx.x;
    const int tid = threadIdx.x;
    __shared__ float red[256];
    const size_t base = (size_t)row * Dn;

    float vals[4];
    float s = 0.f;
    #pragma unroll
    for (int i = 0; i < 4; ++i) {
        const int c = tid + i * 256;
        vals[i] = u2f(a[base + c]) + u2f(r[base + c]);
        s += vals[i];
    }
    red[tid] = s;
    __syncthreads();
    for (int o = 128; o > 0; o >>= 1) {
        if (tid < o) red[tid] += red[tid + o];
        __syncthreads();
    }
    const float mu = red[0] * (1.f / Dn);
    __syncthreads();

    float vs = 0.f;
    #pragma unroll
    for (int i = 0; i < 4; ++i) { const float d = vals[i] - mu; vs += d * d; }
    red[tid] = vs;
    __syncthreads();
    for (int o = 128; o > 0; o >>= 1) {
        if (tid < o) red[tid] += red[tid + o];
        __syncthreads();
    }
    const float rstd = rsqrtf(red[0] * (1.f / Dn) + EPSf);

    #pragma unroll
    for (int i = 0; i < 4; ++i) {
        const int c = tid + i * 256;
        out[base + c] = (vals[i] - mu) * rstd * g[c] + be[c];
    }
}

// ---------------------------------------------------------------------------
extern "C" void kernel_launch(void* const* d_in, const int* in_sizes, int n_in,
                              void* d_out, int out_size, void* d_ws, size_t ws_size,
                              hipStream_t stream)
{
    const float* tgt  = (const float*)d_in[0];
    const float* Wqkv = (const float*)d_in[1];
    const float* bqkv = (const float*)d_in[2];
    const float* Wo   = (const float*)d_in[3];
    const float* bo   = (const float*)d_in[4];
    const float* W1   = (const float*)d_in[5];
    const float* b1   = (const float*)d_in[6];
    const float* W2   = (const float*)d_in[7];
    const float* b2   = (const float*)d_in[8];
    const float* g1   = (const float*)d_in[9];
    const float* be1  = (const float*)d_in[10];
    const float* g2   = (const float*)d_in[11];
    const float* be2  = (const float*)d_in[12];
    // d_in[13] (tgt_mask) == tril(ones): attention uses col<=row instead.
    float* out = (float*)d_out;
    (void)in_sizes; (void)n_in; (void)out_size; (void)ws_size;

    const int M = Bn * Tn;               // 6400

    // ---- workspace layout (liveness-aliased, <128 MiB total) ----
    char* w = (char*)d_ws;
    ushort_t* tgt_bf  = (ushort_t*)(w);
    ushort_t* Wqkv_bf = (ushort_t*)(w + 13107200);
    ushort_t* Wo_bf   = (ushort_t*)(w + 19398656);
    ushort_t* W1_bf   = (ushort_t*)(w + 21495808);
    ushort_t* W2_bf   = (ushort_t*)(w + 29884416);

    ushort_t* qb    = (ushort_t*)(w + 38273024);         // 16,777,216 each
    ushort_t* kb    = (ushort_t*)(w + 55050240);
    ushort_t* vtb   = (ushort_t*)(w + 71827456);
    ushort_t* hbuf  = (ushort_t*)(w + 38273024);         // 52,428,800
    ushort_t* qkvb  = (ushort_t*)(w + 88604672);         // 39,321,600
    ushort_t* ctxb  = (ushort_t*)(w + 88604672);         // 13,107,200
    ushort_t* tgt2b = (ushort_t*)(w + 101711872);        // 13,107,200
    ushort_t* ffb   = (ushort_t*)(w + 101711872);
    ushort_t* x_bf  = (ushort_t*)(w + 114819072);        // 13,107,200
    float2*   ropetab = (float2*)(w + 127926272);        // 12,800

    // ---- 0. all fp32 -> bf16 conversions + rope table, one launch ----
    Conv5 cfg;
    cfg.seg[0] = { tgt,  tgt_bf,  M * Dn / 4 };
    cfg.seg[1] = { Wqkv, Wqkv_bf, 3 * Dn * Dn / 4 };
    cfg.seg[2] = { Wo,   Wo_bf,   Dn * Dn / 4 };
    cfg.seg[3] = { W1,   W1_bf,   DFFn * Dn / 4 };
    cfg.seg[4] = { W2,   W2_bf,   Dn * DFFn / 4 };
    cfg.tab    = ropetab;
    const int total4 = (M * Dn + 3 * Dn * Dn + Dn * Dn + 2 * DFFn * Dn) / 4;
    conv_bf16_multi<<<(total4 + 255) / 256 + 1, 256, 0, stream>>>(cfg);

    // 1. qkv GEMM -> qkvb (plain coalesced epilogue), 128x128 2-phase core,
    //    50x24 = 1200 blocks, 2 blocks/CU, XCD affinity.
    gemm128_2p<false, false, ushort_t><<<(M / 128) * (3 * Dn / 128), 256, 0, stream>>>(
        tgt_bf, Wqkv_bf, bqkv, nullptr, qkvb, M, 3 * Dn, Dn, 3 * Dn / 128, 1);
    // 2. RoPE + head-split + V-transpose (memory-bound), 1024 blocks.
    rope_split<<<Bn * Hn, 256, 0, stream>>>(qkvb, ropetab, qb, kb, vtb);
    // 3. MFMA attention -> ctx bf16
    attn_mfma<<<Bn * Hn, 256, 0, stream>>>(qb, kb, vtb, ctxb);
    // 4. tgt2 = ctx @ Wo^T + bo + tgt (bf16 out, residual fused),
    //    128x128 2-phase core: 50x8 = 400 blocks, 2 blocks/CU.
    gemm128_2p<false, true, ushort_t><<<(M / 128) * (Dn / 128), 256, 0, stream>>>(
        ctxb, Wo_bf, bo, tgt_bf, tgt2b, M, Dn, Dn, Dn / 128, 1);
    // 5. x_bf = LN(tgt2)  (residual already added in step 4)
    ln_single<<<M, 256, 0, stream>>>(tgt2b, g1, be1, x_bf);
    // 6. h = relu(x @ W1^T + b1), 128x128 2-phase core, 50x32 = 1600 blocks,
    //    2 blocks/CU, linear map (affinity raised W1 FETCH in earlier session).
    gemm128_2p<true, false, ushort_t><<<(M / 128) * (DFFn / 128), 256, 0, stream>>>(
        x_bf, W1_bf, b1, nullptr, hbuf, M, DFFn, Dn, DFFn / 128, 0);
    // 7. ff = h @ W2^T + b2 (bf16 out), 128x128 2-phase core, K=4096,
    //    50x8 = 400 blocks, 2 blocks/CU.
    gemm128_2p<false, false, ushort_t><<<(M / 128) * (Dn / 128), 256, 0, stream>>>(
        hbuf, W2_bf, b2, nullptr, ffb, M, Dn, DFFn, Dn / 128, 1);
    // 8. out = LN(x + ff) (fp32 out)
    add_ln2<<<M, 256, 0, stream>>>(x_bf, ffb, g2, be2, out);
}

// Round 9
// 372.954 us; speedup vs baseline: 1.0807x; 1.0807x over previous
//
#include <hip/hip_runtime.h>
#include <math.h>

// Problem shape (TransformerDecoderLayer_9569187135641) — fp32 I/O,
// bf16 MFMA internals.
#define Bn   64
#define Tn   100
#define Tp   128          // T padded to MFMA tiling
#define Dn   1024
#define Hn   16
#define HDn  64
#define DFFn 4096
#define EPSf 1e-5f

typedef unsigned short ushort_t;
typedef __attribute__((ext_vector_type(8))) __bf16 bf16x8;
typedef __attribute__((ext_vector_type(4))) float f32x4;

__device__ __forceinline__ float u2f(ushort_t u) {
    union { unsigned int i; float f; } v; v.i = ((unsigned int)u) << 16; return v.f;
}
__device__ __forceinline__ ushort_t f2bf(float f) {   // RNE f32 -> bf16 bits
    union { float f; unsigned int u; } v; v.f = f;
    unsigned int r = v.u + 0x7FFFu + ((v.u >> 16) & 1u);
    return (ushort_t)(r >> 16);
}

// async global(16B/lane) -> LDS; LDS dest = wave-uniform base + lane*16.
__device__ __forceinline__ void gload_lds16(const void* g, void* l) {
    __builtin_amdgcn_global_load_lds(
        (const __attribute__((address_space(1))) unsigned int*)g,
        (__attribute__((address_space(3))) unsigned int*)l,
        16, 0, 0);
}

#define VMWAIT_(n) asm volatile("s_waitcnt vmcnt(" #n ")" ::: "memory")
#define VMWAIT(n)  VMWAIT_(n)

// ---------------------------------------------------------------------------
// Fused fp32 -> bf16 conversion of up to 5 buffers + RoPE sincos table
// (last block) in one launch. tab[t][f] = (cos, sin)(t * 10000^(-f/16)),
// t < 100, f < 16.
// ---------------------------------------------------------------------------
struct ConvSeg { const float* src; ushort_t* dst; int n4; };
struct Conv5   { ConvSeg seg[5]; float2* tab; };

__global__ __launch_bounds__(256) void conv_bf16_multi(Conv5 cfg)
{
    if (blockIdx.x == gridDim.x - 1) {
        for (int e = threadIdx.x; e < Tn * 16; e += 256) {
            const int t = e >> 4, f = e & 15;
            float s, c;
            sincosf((float)t * exp2f(-0.83048202f * (float)f), &s, &c);
            cfg.tab[e] = make_float2(c, s);
        }
        return;
    }
    int i = blockIdx.x * 256 + threadIdx.x;
    #pragma unroll
    for (int s = 0; s < 5; ++s) {
        const int n = cfg.seg[s].n4;
        if (i < n) {
            float4 v = ((const float4*)cfg.seg[s].src)[i];
            ushort4 o;
            o.x = f2bf(v.x); o.y = f2bf(v.y); o.z = f2bf(v.z); o.w = f2bf(v.w);
            ((ushort4*)cfg.seg[s].dst)[i] = o;
            return;
        }
        i -= n;
    }
}

// ---------------------------------------------------------------------------
// Tile map (shared): swz=1 -> XCD-affinity (groups of 8 row-tiles; all
// col-blocks of one row land on one XCD). swz=0 -> plain col-fast linear.
// ---------------------------------------------------------------------------
#define GEMM_TILE_MAP(gx_, gy_, swz_)                                        \
    const int L  = blockIdx.x;                                               \
    int rowt, colt;                                                          \
    if (swz_) {                                                              \
        const int group = L / (8 * (gx_));                                   \
        int l = L - group * 8 * (gx_);                                       \
        const int rem = (gy_) - group * 8;                                   \
        if (rem >= 8) { rowt = group * 8 + (l & 7); colt = l >> 3; }         \
        else          { rowt = group * 8 + l % rem; colt = l / rem; }        \
    } else { rowt = L / (gx_); colt = L - rowt * (gx_); }

// ---------------------------------------------------------------------------
// 128x128 1-phase pipelined core (r9): 4 waves (2x2, per-wave 64x64), BK=64,
// A double-buffered + B TRIPLE-buffered -> ONE barrier pair per K-tile
// (r8's 2-phase had 4 barriers/K-tile; r3/r7 established barrier count as
// the binding cost at constant MFMA-per-phase). LDS 80 KiB -> 2 blocks/CU
// (exactly 160 KiB).
//
// Phase t: {ds_read af(t) from As[t&1], bfr(t) from Bs[t%3];
//           issue gload A(t+1)->As[(t+1)&1], B(t+2)->Bs[(t+2)%3];
//           barrier; lgkmcnt(0); 32 MFMA/wave; vmcnt(4); barrier}
// Aliasing: reads Bs[t%3] vs writes Bs[(t+2)%3] vs landing B(t+1) in
// Bs[(t+1)%3] — all distinct mod 3. A: reads As[t&1], writes As[t&1 ^ 1];
// As[t&1^1]'s previous reads (tile t-1) completed before t-1's lgkmcnt(0)
// + trailing barrier, which precedes any tile-t gload issue.
// FIFO vmcnt: end of tile t queue = [B(t+1)x4, A(t+1)x4, B(t+2)x4];
// vmcnt(4) => A(t+1), B(t+1) landed, B(t+2) stays in flight (never 0
// mid-loop). Tile NT-2 (no stB): queue [B(NT-1)x4, A(NT-1)x4] -> vmcnt(0).
// XOR-chunk source-side swizzle (SQ_LDS_BANK_CONFLICT = 0) unchanged.
// ---------------------------------------------------------------------------
template<bool RELU, bool ADDRES, typename OutT>
__global__ __launch_bounds__(256, 2) void gemm128_1p(const ushort_t* __restrict__ A,
                                                     const ushort_t* __restrict__ Bm,
                                                     const float* __restrict__ bias,
                                                     const ushort_t* __restrict__ res,
                                                     OutT* __restrict__ C,
                                                     int M, int N, int K,
                                                     int gx, int swz)
{
    __shared__ __align__(16) ushort_t As[2][128 * 64];   // 32 KiB
    __shared__ __align__(16) ushort_t Bs[3][128 * 64];   // 48 KiB

    const int gy = M >> 7;
    GEMM_TILE_MAP(gx, gy, swz)

    const int tid  = threadIdx.x;
    const int lane = tid & 63;
    const int wave = tid >> 6;
    const int wrow = (wave >> 1) * 64;
    const int wcol = (wave & 1) * 64;
    const int row0 = rowt * 128;
    const int col0 = colt * 128;
    const int frow = lane & 15;
    const int g    = lane >> 4;

    auto stage = [&](const ushort_t* src, int rowbase, ushort_t* lds) {
        #pragma unroll
        for (int i = 0; i < 4; ++i) {
            const int idx = i * 256 + tid;
            const int row = idx >> 3;
            const int gc  = (idx & 7) ^ (row & 7);
            gload_lds16(src + (size_t)(rowbase + row) * K + gc * 8, lds + idx * 8);
        }
    };

    f32x4 acc[4][4] = {};

    const int NT = K >> 6;
    // prologue: B(0), A(0), B(1); wait B(0)+A(0) landed (B(1) stays in flight).
    stage(Bm, col0, &Bs[0][0]);
    stage(A,  row0, &As[0][0]);
    if (NT > 1) { stage(Bm + 64, col0, &Bs[1][0]); VMWAIT(4); }
    else        { VMWAIT(0); }
    __builtin_amdgcn_s_barrier();

    for (int t = 0; t < NT; ++t) {
        const int  bufA = t & 1;
        const int  bufB = t % 3;
        const bool stA  = (t + 1 < NT);
        const bool stB  = (t + 2 < NT);

        bf16x8 bfr[4][2], af[4][2];
        #pragma unroll
        for (int j = 0; j < 4; ++j)
            #pragma unroll
            for (int kk = 0; kk < 2; ++kk) {
                const int rb = wcol + j * 16 + frow;
                const int ch = kk * 4 + g;
                bfr[j][kk] = *(const bf16x8*)&Bs[bufB][rb * 64 + (ch ^ (rb & 7)) * 8];
            }
        #pragma unroll
        for (int m = 0; m < 4; ++m)
            #pragma unroll
            for (int kk = 0; kk < 2; ++kk) {
                const int ra = wrow + m * 16 + frow;
                const int ch = kk * 4 + g;
                af[m][kk] = *(const bf16x8*)&As[bufA][ra * 64 + (ch ^ (ra & 7)) * 8];
            }
        if (stA) stage(A + (t + 1) * 64,  row0, &As[bufA ^ 1][0]);
        if (stB) stage(Bm + (t + 2) * 64, col0, &Bs[(t + 2) % 3][0]);
        __builtin_amdgcn_s_barrier();
        asm volatile("s_waitcnt lgkmcnt(0)" ::: "memory");
        __builtin_amdgcn_sched_barrier(0);
        __builtin_amdgcn_s_setprio(1);
        #pragma unroll
        for (int m = 0; m < 4; ++m)
            #pragma unroll
            for (int j = 0; j < 4; ++j)
                #pragma unroll
                for (int kk = 0; kk < 2; ++kk)
                    acc[m][j] = __builtin_amdgcn_mfma_f32_16x16x32_bf16(
                        af[m][kk], bfr[j][kk], acc[m][j], 0, 0, 0);
        __builtin_amdgcn_s_setprio(0);
        __builtin_amdgcn_sched_barrier(0);
        if (stB)      { VMWAIT(4); }
        else if (stA) { VMWAIT(0); }
        __builtin_amdgcn_s_barrier();
    }

    const int crow = (lane >> 4) * 4;
    const int ccol = lane & 15;
    #pragma unroll
    for (int i = 0; i < 4; ++i) {
        #pragma unroll
        for (int r = 0; r < 4; ++r) {
            const int row = row0 + wrow + i * 16 + crow + r;
            #pragma unroll
            for (int j = 0; j < 4; ++j) {
                const int col = col0 + wcol + j * 16 + ccol;
                float v = acc[i][j][r] + bias[col];
                if constexpr (ADDRES) v += u2f(res[(size_t)row * N + col]);
                if constexpr (RELU) v = fmaxf(v, 0.f);
                if constexpr (sizeof(OutT) == 2)
                    C[(size_t)row * N + col] = (OutT)f2bf(v);
                else
                    C[(size_t)row * N + col] = (OutT)v;
            }
        }
    }
}

// ---------------------------------------------------------------------------
// RoPE + head-split + V-transpose, decoupled from the GEMM (r5 post-mortem:
// the fused epilogue was the qkv bottleneck, invariant to K-loop structure).
// One block per (b,h). Reads qkvb[6400][3072]; writes:
//   q,k: (bh, t<100, 64)   — RoPE'd, coalesced 2B stores in 64B runs
//   vt:  (bh, d, t padded to 128) — transposed via padded LDS (conflict-free),
//        256B contiguous row stores, pad t in [100,128) zero-filled.
// ---------------------------------------------------------------------------
__global__ __launch_bounds__(256) void rope_split(const ushort_t* __restrict__ qkv,
                                                  const float2*  __restrict__ tab,
                                                  ushort_t* __restrict__ q,
                                                  ushort_t* __restrict__ k,
                                                  ushort_t* __restrict__ vt)
{
    __shared__ ushort_t vls[64 * 130];           // padded: stride 130 ushorts

    const int bh  = blockIdx.x;                  // 0..1023
    const int b   = bh >> 4, h = bh & 15;
    const int tid = threadIdx.x;
    const size_t rowbase = (size_t)b * Tn * (3 * Dn) + h * HDn;

    // ---- v load (coalesced) -> LDS transposed ----
    const ushort_t* vsrc = qkv + rowbase + 2 * Dn;
    for (int idx = tid; idx < Tn * 64; idx += 256) {
        const int t = idx >> 6, d = idx & 63;
        vls[d * 130 + t] = vsrc[(size_t)t * (3 * Dn) + d];
    }

    // ---- q and k with RoPE (no LDS dependency) ----
    #pragma unroll
    for (int s = 0; s < 2; ++s) {
        const ushort_t* src = qkv + rowbase + s * Dn;
        ushort_t* dst = (s ? k : q) + (size_t)bh * Tp * HDn;
        for (int idx = tid; idx < Tn * 32; idx += 256) {
            const int t = idx >> 5, p = idx & 31;
            const unsigned int xi =
                *(const unsigned int*)&src[(size_t)t * (3 * Dn) + 2 * p];
            const float x1 = u2f((ushort_t)(xi & 0xffffu));
            const float x2 = u2f((ushort_t)(xi >> 16));
            const float2 cs = tab[t * 16 + (p & 15)];
            dst[t * 64 + p]      = f2bf(x1 * cs.x - x2 * cs.y);
            dst[t * 64 + 32 + p] = f2bf(x1 * cs.y + x2 * cs.x);
        }
    }

    __syncthreads();

    // ---- vt store: 64 rows x 128 cols, contiguous 256B per row ----
    ushort_t* vdst = vt + (size_t)bh * HDn * Tp;
    for (int idx = tid; idx < 64 * 64; idx += 256) {
        const int d  = idx >> 6;
        const int tt = (idx & 63) * 2;
        ushort2 o;
        o.x = (tt     < Tn) ? vls[d * 130 + tt]     : (ushort_t)0;
        o.y = (tt + 1 < Tn) ? vls[d * 130 + tt + 1] : (ushort_t)0;
        *(ushort2*)&vdst[d * Tp + tt] = o;
    }
}

// ---------------------------------------------------------------------------
// MFMA flash attention (r4-verified): one block (4 waves) per (b,h).
// ---------------------------------------------------------------------------
__global__ __launch_bounds__(256) void attn_mfma(const ushort_t* __restrict__ q,
                                                 const ushort_t* __restrict__ k,
                                                 const ushort_t* __restrict__ vt,
                                                 ushort_t* __restrict__ ctx)
{
    __shared__ __align__(16) ushort_t sm[24576];   // 48 KB

    const int bh   = blockIdx.x;
    const int b    = bh >> 4, h = bh & 15;
    const int tid  = threadIdx.x;
    const int wave = tid >> 6;
    const int lane = tid & 63;
    const int c    = lane & 15;
    const int g    = lane >> 4;
    const int R0   = wave * 32;

    const ushort_t* qg = q  + (size_t)bh * Tp * HDn;
    const ushort_t* kg = k  + (size_t)bh * Tp * HDn;
    const ushort_t* vg = vt + (size_t)bh * HDn * Tp;
    for (int s = wave; s < 16; s += 4) {
        const int idx = s * 64 + lane;
        { const int row = idx >> 3, pc = idx & 7, gc = pc ^ (row & 7);
          gload_lds16(qg + row * 64 + gc * 8, &sm[idx * 8]);
          gload_lds16(kg + row * 64 + gc * 8, &sm[8192 + idx * 8]); }
        { const int row = idx >> 4, pc = idx & 15, gc = pc ^ (row & 15);
          gload_lds16(vg + row * 128 + gc * 8, &sm[16384 + idx * 8]); }
    }
    __syncthreads();

    // ---- S = Q K^T ----
    f32x4 acc[2][8] = {};
    #pragma unroll
    for (int ks = 0; ks < 2; ++ks) {
        const int cb = ks * 4;
        bf16x8 aq[2];
        #pragma unroll
        for (int i = 0; i < 2; ++i) {
            const int row = R0 + i * 16 + c;
            const int ph  = (cb + g) ^ (row & 7);
            aq[i] = *(const bf16x8*)&sm[row * 64 + ph * 8];
        }
        #pragma unroll
        for (int j = 0; j < 8; ++j) {
            const int row = j * 16 + c;
            const int ph  = (cb + g) ^ (row & 7);
            const bf16x8 bk = *(const bf16x8*)&sm[8192 + row * 64 + ph * 8];
            acc[0][j] = __builtin_amdgcn_mfma_f32_16x16x32_bf16(aq[0], bk, acc[0][j], 0, 0, 0);
            acc[1][j] = __builtin_amdgcn_mfma_f32_16x16x32_bf16(aq[1], bk, acc[1][j], 0, 0, 0);
        }
    }
    __syncthreads();

    // ---- softmax + P(bf16) into sm[0..16384) ----
    float linv[2][4];
    #pragma unroll
    for (int i = 0; i < 2; ++i) {
        #pragma unroll
        for (int r = 0; r < 4; ++r) {
            const int row = R0 + i * 16 + g * 4 + r;
            float sv[8], m = -1e30f;
            #pragma unroll
            for (int j = 0; j < 8; ++j) {
                const int col = j * 16 + c;
                const float s = acc[i][j][r] * 0.125f;
                sv[j] = (col <= row) ? s : -1e30f;
                m = fmaxf(m, sv[j]);
            }
            #pragma unroll
            for (int msk = 1; msk < 16; msk <<= 1) m = fmaxf(m, __shfl_xor(m, msk));
            float l = 0.f;
            #pragma unroll
            for (int j = 0; j < 8; ++j) {
                const int col = j * 16 + c;
                const float p = (col <= row) ? __expf(sv[j] - m) : 0.f;
                sv[j] = p; l += p;
            }
            #pragma unroll
            for (int msk = 1; msk < 16; msk <<= 1) l += __shfl_xor(l, msk);
            linv[i][r] = 1.f / l;
            #pragma unroll
            for (int j = 0; j < 8; ++j) {
                const int chunk = j * 2 + (c >> 3);
                const int ph    = chunk ^ (row & 15);
                sm[row * 128 + ph * 8 + (c & 7)] = f2bf(sv[j]);
            }
        }
    }
    __syncthreads();

    // ---- ctx = P Vt^T ----
    f32x4 acc2[2][4] = {};
    #pragma unroll
    for (int ks = 0; ks < 4; ++ks) {
        const int cb = ks * 4;
        bf16x8 ap[2];
        #pragma unroll
        for (int i = 0; i < 2; ++i) {
            const int row = R0 + i * 16 + c;
            const int ph  = (cb + g) ^ (row & 15);
            ap[i] = *(const bf16x8*)&sm[row * 128 + ph * 8];
        }
        #pragma unroll
        for (int n = 0; n < 4; ++n) {
            const int row = n * 16 + c;
            const int ph  = (cb + g) ^ (row & 15);
            const bf16x8 bv = *(const bf16x8*)&sm[16384 + row * 128 + ph * 8];
            acc2[0][n] = __builtin_amdgcn_mfma_f32_16x16x32_bf16(ap[0], bv, acc2[0][n], 0, 0, 0);
            acc2[1][n] = __builtin_amdgcn_mfma_f32_16x16x32_bf16(ap[1], bv, acc2[1][n], 0, 0, 0);
        }
    }

    #pragma unroll
    for (int i = 0; i < 2; ++i) {
        #pragma unroll
        for (int r = 0; r < 4; ++r) {
            const int row = R0 + i * 16 + g * 4 + r;
            if (row < Tn) {
                const float s = linv[i][r];
                #pragma unroll
                for (int n = 0; n < 4; ++n) {
                    const int col = n * 16 + c;
                    ctx[(size_t)(b * Tn + row) * Dn + h * HDn + col] =
                        f2bf(acc2[i][n][r] * s);
                }
            }
        }
    }
}

// ---------------------------------------------------------------------------
// LN variants.
// ---------------------------------------------------------------------------
__global__ __launch_bounds__(256) void ln_single(const ushort_t* __restrict__ a,
                                                 const float* __restrict__ g,
                                                 const float* __restrict__ be,
                                                 ushort_t* __restrict__ out_bf)
{
    const int row = blockIdx.x;
    const int tid = threadIdx.x;
    __shared__ float red[256];
    const size_t base = (size_t)row * Dn;

    float vals[4];
    float s = 0.f;
    #pragma unroll
    for (int i = 0; i < 4; ++i) {
        const int c = tid + i * 256;
        vals[i] = u2f(a[base + c]);
        s += vals[i];
    }
    red[tid] = s;
    __syncthreads();
    for (int o = 128; o > 0; o >>= 1) {
        if (tid < o) red[tid] += red[tid + o];
        __syncthreads();
    }
    const float mu = red[0] * (1.f / Dn);
    __syncthreads();

    float vs = 0.f;
    #pragma unroll
    for (int i = 0; i < 4; ++i) { const float d = vals[i] - mu; vs += d * d; }
    red[tid] = vs;
    __syncthreads();
    for (int o = 128; o > 0; o >>= 1) {
        if (tid < o) red[tid] += red[tid + o];
        __syncthreads();
    }
    const float rstd = rsqrtf(red[0] * (1.f / Dn) + EPSf);

    #pragma unroll
    for (int i = 0; i < 4; ++i) {
        const int c = tid + i * 256;
        out_bf[base + c] = f2bf((vals[i] - mu) * rstd * g[c] + be[c]);
    }
}

__global__ __launch_bounds__(256) void add_ln2(const ushort_t* __restrict__ a,
                                               const ushort_t* __restrict__ r,
                                               const float* __restrict__ g,
                                               const float* __restrict__ be,
                                               float* __restrict__ out)
{
    const int row = blockIdx.x;
    const int tid = threadIdx.x;
    __shared__ float red[256];
    const size_t base = (size_t)row * Dn;

    float vals[4];
    float s = 0.f;
    #pragma unroll
    for (int i = 0; i < 4; ++i) {
        const int c = tid + i * 256;
        vals[i] = u2f(a[base + c]) + u2f(r[base + c]);
        s += vals[i];
    }
    red[tid] = s;
    __syncthreads();
    for (int o = 128; o > 0; o >>= 1) {
        if (tid < o) red[tid] += red[tid + o];
        __syncthreads();
    }
    const float mu = red[0] * (1.f / Dn);
    __syncthreads();

    float vs = 0.f;
    #pragma unroll
    for (int i = 0; i < 4; ++i) { const float d = vals[i] - mu; vs += d * d; }
    red[tid] = vs;
    __syncthreads();
    for (int o = 128; o > 0; o >>= 1) {
        if (tid < o) red[tid] += red[tid + o];
        __syncthreads();
    }
    const float rstd = rsqrtf(red[0] * (1.f / Dn) + EPSf);

    #pragma unroll
    for (int i = 0; i < 4; ++i) {
        const int c = tid + i * 256;
        out[base + c] = (vals[i] - mu) * rstd * g[c] + be[c];
    }
}

// ---------------------------------------------------------------------------
extern "C" void kernel_launch(void* const* d_in, const int* in_sizes, int n_in,
                              void* d_out, int out_size, void* d_ws, size_t ws_size,
                              hipStream_t stream)
{
    const float* tgt  = (const float*)d_in[0];
    const float* Wqkv = (const float*)d_in[1];
    const float* bqkv = (const float*)d_in[2];
    const float* Wo   = (const float*)d_in[3];
    const float* bo   = (const float*)d_in[4];
    const float* W1   = (const float*)d_in[5];
    const float* b1   = (const float*)d_in[6];
    const float* W2   = (const float*)d_in[7];
    const float* b2   = (const float*)d_in[8];
    const float* g1   = (const float*)d_in[9];
    const float* be1  = (const float*)d_in[10];
    const float* g2   = (const float*)d_in[11];
    const float* be2  = (const float*)d_in[12];
    // d_in[13] (tgt_mask) == tril(ones): attention uses col<=row instead.
    float* out = (float*)d_out;
    (void)in_sizes; (void)n_in; (void)out_size; (void)ws_size;

    const int M = Bn * Tn;               // 6400

    // ---- workspace layout (liveness-aliased, <128 MiB total) ----
    char* w = (char*)d_ws;
    ushort_t* tgt_bf  = (ushort_t*)(w);
    ushort_t* Wqkv_bf = (ushort_t*)(w + 13107200);
    ushort_t* Wo_bf   = (ushort_t*)(w + 19398656);
    ushort_t* W1_bf   = (ushort_t*)(w + 21495808);
    ushort_t* W2_bf   = (ushort_t*)(w + 29884416);

    ushort_t* qb    = (ushort_t*)(w + 38273024);         // 16,777,216 each
    ushort_t* kb    = (ushort_t*)(w + 55050240);
    ushort_t* vtb   = (ushort_t*)(w + 71827456);
    ushort_t* hbuf  = (ushort_t*)(w + 38273024);         // 52,428,800
    ushort_t* qkvb  = (ushort_t*)(w + 88604672);         // 39,321,600
    ushort_t* ctxb  = (ushort_t*)(w + 88604672);         // 13,107,200
    ushort_t* tgt2b = (ushort_t*)(w + 101711872);        // 13,107,200
    ushort_t* ffb   = (ushort_t*)(w + 101711872);
    ushort_t* x_bf  = (ushort_t*)(w + 114819072);        // 13,107,200
    float2*   ropetab = (float2*)(w + 127926272);        // 12,800

    // ---- 0. all fp32 -> bf16 conversions + rope table, one launch ----
    Conv5 cfg;
    cfg.seg[0] = { tgt,  tgt_bf,  M * Dn / 4 };
    cfg.seg[1] = { Wqkv, Wqkv_bf, 3 * Dn * Dn / 4 };
    cfg.seg[2] = { Wo,   Wo_bf,   Dn * Dn / 4 };
    cfg.seg[3] = { W1,   W1_bf,   DFFn * Dn / 4 };
    cfg.seg[4] = { W2,   W2_bf,   Dn * DFFn / 4 };
    cfg.tab    = ropetab;
    const int total4 = (M * Dn + 3 * Dn * Dn + Dn * Dn + 2 * DFFn * Dn) / 4;
    conv_bf16_multi<<<(total4 + 255) / 256 + 1, 256, 0, stream>>>(cfg);

    // 1. qkv GEMM -> qkvb (plain coalesced epilogue), 128x128 1-phase core,
    //    50x24 = 1200 blocks, 2 blocks/CU, XCD affinity.
    gemm128_1p<false, false, ushort_t><<<(M / 128) * (3 * Dn / 128), 256, 0, stream>>>(
        tgt_bf, Wqkv_bf, bqkv, nullptr, qkvb, M, 3 * Dn, Dn, 3 * Dn / 128, 1);
    // 2. RoPE + head-split + V-transpose (memory-bound), 1024 blocks.
    rope_split<<<Bn * Hn, 256, 0, stream>>>(qkvb, ropetab, qb, kb, vtb);
    // 3. MFMA attention -> ctx bf16
    attn_mfma<<<Bn * Hn, 256, 0, stream>>>(qb, kb, vtb, ctxb);
    // 4. tgt2 = ctx @ Wo^T + bo + tgt (bf16 out, residual fused),
    //    128x128 1-phase core: 50x8 = 400 blocks, 2 blocks/CU.
    gemm128_1p<false, true, ushort_t><<<(M / 128) * (Dn / 128), 256, 0, stream>>>(
        ctxb, Wo_bf, bo, tgt_bf, tgt2b, M, Dn, Dn, Dn / 128, 1);
    // 5. x_bf = LN(tgt2)  (residual already added in step 4)
    ln_single<<<M, 256, 0, stream>>>(tgt2b, g1, be1, x_bf);
    // 6. h = relu(x @ W1^T + b1), 128x128 1-phase core, 50x32 = 1600 blocks,
    //    2 blocks/CU, linear map.
    gemm128_1p<true, false, ushort_t><<<(M / 128) * (DFFn / 128), 256, 0, stream>>>(
        x_bf, W1_bf, b1, nullptr, hbuf, M, DFFn, Dn, DFFn / 128, 0);
    // 7. ff = h @ W2^T + b2 (bf16 out), 128x128 1-phase core, K=4096,
    //    50x8 = 400 blocks, 2 blocks/CU.
    gemm128_1p<false, false, ushort_t><<<(M / 128) * (Dn / 128), 256, 0, stream>>>(
        hbuf, W2_bf, b2, nullptr, ffb, M, Dn, DFFn, Dn / 128, 1);
    // 8. out = LN(x + ff) (fp32 out)
    add_ln2<<<M, 256, 0, stream>>>(x_bf, ffb, g2, be2, out);
}